// Round 7
// baseline (248.402 us; speedup 1.0000x reference)
//
#include <hip/hip_runtime.h>

// PPNM layer: out = m + b_s[:,None] * m*m, m = x @ W
//   x: [B, 16] fp32, W: [16, 224] fp32, b_s: [B] fp32, out: [B, 224] fp32
//
// Memory-bound: 235 MB write + ~18 MB read => ~40 us write floor at 6.3 TB/s.
//
// R8 vs R7 (245.3 us): single variable, PPB 128 -> 256.
//  - R7 structure is already clean: ONE barrier per block, placed BEFORE
//    any stores (drains only the unavoidable stage-load wait); then
//    32*(5 ds_read + 68 FMA + 1 fire-and-forget dwordx4 store), no
//    further waits until retire. Duty model per CU: LDS ~18 us, VALU
//    ~14 us, HBM-write ~36 us -> write pipe binding, rest hidden.
//  - Remaining O(bodies) costs: 2 blocks/CU residency (7-wave blocks,
//    VGPR in (64,128] -> 16-wave cap) => 2048 blocks = 4 generations;
//    at each boundary both resident blocks stage+barrier simultaneously
//    (~900 cyc uncovered bubble), and every block re-loads the 64-VGPR
//    W fragment. PPB=256 halves generations (2), blocks (1024), Wf
//    reloads, and barriers. LDS 17.4 KB/block (2 blocks = 35 KB << 160).
//  - Store mapping per wave and FMA order per output unchanged -> absmax
//    unchanged. Registers stay under the 128 cap -> occupancy unchanged.
//  - Pre-committed: if |delta| <= 2 us, structural floor reached ->
//    ROOFLINE call next round.

#define LBANDS 224
#define EMEMB  16
#define GROUPS 56                   // band groups: thread owns bands [4g, 4g+4)
#define PPHASE 8                    // pixel phases
#define NTHREADS (GROUPS * PPHASE)  // 448 = 7 full waves
#define PPB    256                  // pixels per block (thread: 32 pixels)
#define XCHUNKS (PPB * 4)           // 1024 float4 chunks of x per block

__global__ __launch_bounds__(NTHREADS, 4) void ppnm_kernel(
    const float* __restrict__ x,    // [B, 16]
    const float* __restrict__ w,    // [16, 224]
    const float* __restrict__ bs,   // [B]
    float* __restrict__ out,        // [B, 224]
    int B)
{
    const int t  = threadIdx.x;
    const int g  = t % GROUPS;   // band group: bands [4g, 4g+4)
    const int pw = t / GROUPS;   // pixel phase: handles pixels pw+8j, j=0..31

    const int body = blockIdx.x;
    if (body * PPB >= B) return;

    __shared__ float4 xsh[XCHUNKS];   // [pixel*4 + quarter]  (16 KB)
    __shared__ float  bsh[PPB];       // (1 KB)

    // --- cooperative stage: issue all staging loads first ---
    // 1024 chunks over 448 threads: t, t+448, and (t<128) t+896.
    const float4* xv = reinterpret_cast<const float4*>(x);
    const long base = (long)body * XCHUNKS;
    const float4 v0 = xv[base + t];
    const float4 v1 = xv[base + NTHREADS + t];
    float4 v2 = make_float4(0.f, 0.f, 0.f, 0.f);
    if (t < XCHUNKS - 2 * NTHREADS)                 // chunks 896..1023
        v2 = xv[base + 2 * NTHREADS + t];
    float bv = 0.f;
    if (t < PPB)                                    // bs 0..255
        bv = bs[body * PPB + t];

    // W fragment: Wf[k] = w[k][4g..4g+3]. 64 VGPRs; w is L2-hot (14 KB).
    float4 Wf[EMEMB];
    #pragma unroll
    for (int k = 0; k < EMEMB; ++k) {
        Wf[k] = *reinterpret_cast<const float4*>(w + k * LBANDS + 4 * g);
    }

    xsh[t] = v0;
    xsh[NTHREADS + t] = v1;
    if (t < XCHUNKS - 2 * NTHREADS) xsh[2 * NTHREADS + t] = v2;
    if (t < PPB)                    bsh[t] = bv;
    __syncthreads();   // the ONLY barrier: drains only the stage loads

#define PPNM_FMA4(SCAL, K)                                                    \
        acc.x = fmaf((SCAL), Wf[K].x, acc.x);                                 \
        acc.y = fmaf((SCAL), Wf[K].y, acc.y);                                 \
        acc.z = fmaf((SCAL), Wf[K].z, acc.z);                                 \
        acc.w = fmaf((SCAL), Wf[K].w, acc.w);

    // --- 32 pixels per thread, pure FMA + fire-and-forget stores ---
    #pragma unroll
    for (int j = 0; j < PPB / PPHASE; ++j) {
        const int px = pw + PPHASE * j;          // pixel within body: 0..255
        const float4 xa = xsh[px * 4 + 0];       // broadcast reads (<=2 addrs
        const float4 xb = xsh[px * 4 + 1];       //  per wave = conflict-free)
        const float4 xc = xsh[px * 4 + 2];
        const float4 xd = xsh[px * 4 + 3];
        const float  sb = bsh[px];

        float4 acc = make_float4(0.f, 0.f, 0.f, 0.f);
        PPNM_FMA4(xa.x,  0) PPNM_FMA4(xa.y,  1)
        PPNM_FMA4(xa.z,  2) PPNM_FMA4(xa.w,  3)
        PPNM_FMA4(xb.x,  4) PPNM_FMA4(xb.y,  5)
        PPNM_FMA4(xb.z,  6) PPNM_FMA4(xb.w,  7)
        PPNM_FMA4(xc.x,  8) PPNM_FMA4(xc.y,  9)
        PPNM_FMA4(xc.z, 10) PPNM_FMA4(xc.w, 11)
        PPNM_FMA4(xd.x, 12) PPNM_FMA4(xd.y, 13)
        PPNM_FMA4(xd.z, 14) PPNM_FMA4(xd.w, 15)

        float4 r;
        r.x = fmaf(sb * acc.x, acc.x, acc.x);
        r.y = fmaf(sb * acc.y, acc.y, acc.y);
        r.z = fmaf(sb * acc.z, acc.z, acc.z);
        r.w = fmaf(sb * acc.w, acc.w, acc.w);

        // body slab = 224 KB contiguous; wave covers 1024B across two
        // adjacent rows -> pure streaming, never awaited.
        *reinterpret_cast<float4*>(out + ((long)(body * PPB + px)) * LBANDS + 4 * g) = r;
    }

#undef PPNM_FMA4
}

extern "C" void kernel_launch(void* const* d_in, const int* in_sizes, int n_in,
                              void* d_out, int out_size, void* d_ws, size_t ws_size,
                              hipStream_t stream) {
    const float* x  = (const float*)d_in[0];   // [B, 16]
    const float* w  = (const float*)d_in[1];   // [16, 224]
    const float* bs = (const float*)d_in[2];   // [B]
    float* out = (float*)d_out;

    const int B = in_sizes[2];                 // 262144

    // One 256-pixel body per block: grid = B/256 = 1024.
    const int grid = (B + PPB - 1) / PPB;
    ppnm_kernel<<<grid, NTHREADS, 0, stream>>>(x, w, bs, out, B);
}

// Round 8
// 245.093 us; speedup vs baseline: 1.0135x; 1.0135x over previous
//
#include <hip/hip_runtime.h>

// PPNM layer: out = m + b_s[:,None] * m*m, m = x @ W
//   x: [B, 16] fp32, W: [16, 224] fp32, b_s: [B] fp32, out: [B, 224] fp32
//
// Memory-bound: 235 MB write + ~18 MB read => ~40 us write floor at 6.3 TB/s.
//
// R9 = revert to R7 (best measured: 245.3 us). R8 (PPB 256) regressed to
// 248.4 -> generation-boundary/Wf-amortization theory dead; per-wait-event
// pool is drained (R3 +32, R6 -31, R7 -12, R8 +3). Final structure:
//  - ONE barrier per block, placed BEFORE any stores: the drain covers
//    only the unavoidable stage-load wait. After it: 16 pixels/thread of
//    pure FMA + fire-and-forget dwordx4 stores, zero waits until retire
//    (the 6.6 TB/s fill kernel's regime).
//  - 128-pixel body staged via one cooperative coalesced read (8 KB x +
//    512 B bs) instead of 56-way-redundant per-thread loads.
//  - Wave stores 1024 contiguous bytes (rows are 896 B, segments abut);
//    LDS reads are <=2 distinct addrs/wave (broadcast, conflict-free).
//  - Duty model/CU: HBM-write ~36 us (binding), LDS ~20, VALU ~14 ->
//    hidden pipes fit under write duty. Kernel-proper ~64 us vs ~40 us
//    floor; no counter-visible lever remains (kernel absent from top-5).
// Session: 295.8 -> 245.3 us. Pre-committed: if this reproduces ~245,
// next round is a ROOFLINE call.

#define LBANDS 224
#define EMEMB  16
#define GROUPS 56                   // band groups: thread owns bands [4g, 4g+4)
#define PPHASE 8                    // pixel phases
#define NTHREADS (GROUPS * PPHASE)  // 448 = 7 full waves
#define PPB    128                  // pixels per block (thread: 16 pixels)
#define XCHUNKS (PPB * 4)           // 512 float4 chunks of x per block

__global__ __launch_bounds__(NTHREADS, 4) void ppnm_kernel(
    const float* __restrict__ x,    // [B, 16]
    const float* __restrict__ w,    // [16, 224]
    const float* __restrict__ bs,   // [B]
    float* __restrict__ out,        // [B, 224]
    int B)
{
    const int t  = threadIdx.x;
    const int g  = t % GROUPS;   // band group: bands [4g, 4g+4)
    const int pw = t / GROUPS;   // pixel phase: handles pixels pw+8j, j=0..15

    const int body = blockIdx.x;
    if (body * PPB >= B) return;

    // Single-buffered x slab + bs slice (one body per block -> no dbuf).
    __shared__ float4 xsh[XCHUNKS];   // [pixel*4 + quarter]
    __shared__ float  bsh[PPB];

    // --- cooperative stage: issue all staging loads first ---
    const float4* xv = reinterpret_cast<const float4*>(x);
    const float4  v0 = xv[body * XCHUNKS + t];                         // chunks 0..447
    float4 v1 = make_float4(0.f, 0.f, 0.f, 0.f);
    if (t < XCHUNKS - NTHREADS)                                        // chunks 448..511
        v1 = xv[body * XCHUNKS + NTHREADS + t];
    float bv = 0.f;
    if (t < PPB)                                                       // bs 0..127
        bv = bs[body * PPB + t];

    // W fragment: Wf[k] = w[k][4g..4g+3]. 64 VGPRs; w is L2-hot (14 KB).
    // Issued after the staging loads so the stage is oldest in vmcnt.
    float4 Wf[EMEMB];
    #pragma unroll
    for (int k = 0; k < EMEMB; ++k) {
        Wf[k] = *reinterpret_cast<const float4*>(w + k * LBANDS + 4 * g);
    }

    xsh[t] = v0;
    if (t < XCHUNKS - NTHREADS) xsh[NTHREADS + t] = v1;
    if (t < PPB)                bsh[t] = bv;
    __syncthreads();   // the ONLY barrier: one drain per block, not per body

#define PPNM_FMA4(SCAL, K)                                                    \
        acc.x = fmaf((SCAL), Wf[K].x, acc.x);                                 \
        acc.y = fmaf((SCAL), Wf[K].y, acc.y);                                 \
        acc.z = fmaf((SCAL), Wf[K].z, acc.z);                                 \
        acc.w = fmaf((SCAL), Wf[K].w, acc.w);

    // --- 16 pixels per thread, pure FMA + fire-and-forget stores ---
    #pragma unroll
    for (int j = 0; j < PPB / PPHASE; ++j) {
        const int px = pw + PPHASE * j;          // pixel within body: 0..127
        const float4 xa = xsh[px * 4 + 0];       // broadcast reads (same addr
        const float4 xb = xsh[px * 4 + 1];       //  across most lanes of wave)
        const float4 xc = xsh[px * 4 + 2];
        const float4 xd = xsh[px * 4 + 3];
        const float  sb = bsh[px];

        float4 acc = make_float4(0.f, 0.f, 0.f, 0.f);
        PPNM_FMA4(xa.x,  0) PPNM_FMA4(xa.y,  1)
        PPNM_FMA4(xa.z,  2) PPNM_FMA4(xa.w,  3)
        PPNM_FMA4(xb.x,  4) PPNM_FMA4(xb.y,  5)
        PPNM_FMA4(xb.z,  6) PPNM_FMA4(xb.w,  7)
        PPNM_FMA4(xc.x,  8) PPNM_FMA4(xc.y,  9)
        PPNM_FMA4(xc.z, 10) PPNM_FMA4(xc.w, 11)
        PPNM_FMA4(xd.x, 12) PPNM_FMA4(xd.y, 13)
        PPNM_FMA4(xd.z, 14) PPNM_FMA4(xd.w, 15)

        float4 r;
        r.x = fmaf(sb * acc.x, acc.x, acc.x);
        r.y = fmaf(sb * acc.y, acc.y, acc.y);
        r.z = fmaf(sb * acc.z, acc.z, acc.z);
        r.w = fmaf(sb * acc.w, acc.w, acc.w);

        // body slab = 112 KB contiguous; wave covers 1024B across two
        // adjacent rows -> pure streaming, never awaited.
        *reinterpret_cast<float4*>(out + (body * PPB + px) * LBANDS + 4 * g) = r;
    }

#undef PPNM_FMA4
}

extern "C" void kernel_launch(void* const* d_in, const int* in_sizes, int n_in,
                              void* d_out, int out_size, void* d_ws, size_t ws_size,
                              hipStream_t stream) {
    const float* x  = (const float*)d_in[0];   // [B, 16]
    const float* w  = (const float*)d_in[1];   // [16, 224]
    const float* bs = (const float*)d_in[2];   // [B]
    float* out = (float*)d_out;

    const int B = in_sizes[2];                 // 262144

    // One 128-pixel body per block: grid = B/128 = 2048.
    const int grid = (B + PPB - 1) / PPB;
    ppnm_kernel<<<grid, NTHREADS, 0, stream>>>(x, w, bs, out, B);
}